// Round 1
// baseline (270.507 us; speedup 1.0000x reference)
//
#include <hip/hip_runtime.h>

constexpr int FRAME_LEN = 130;   // floats per frame
constexpr int HALF      = 65;    // floats per hand block
constexpr int BLOCK     = 256;   // threads per block
constexpr int FPB       = 256;   // frames per block -> chunk = 33280 floats = 16640 float2

__global__ __launch_bounds__(BLOCK)
void hand_sorter_kernel(const float* __restrict__ X, float* __restrict__ out,
                        int n_frames) {
    __shared__ unsigned char s_skip[FPB];
    const int t = threadIdx.x;
    const long long frame0 = (long long)blockIdx.x * FPB;

    // ---- Phase 1: per-frame skip predicate (one thread per frame) ----
    {
        const long long f = frame0 + t;
        if (f < n_frames) {
            const float* fr = X + f * (long long)FRAME_LEN;
            const float h0 = fr[0];
            const float p0 = fr[1];
            const float h1 = fr[HALF];
            const float p1 = fr[HALF + 1];
            const bool nan0 = (h0 != h0);
            const bool nan1 = (h1 != h1);
            const bool no_nan = !nan0 && !nan1;
            const bool eq = (h0 == h1);
            const bool skip =
                (h1 > h0) ||                                   // already ordered
                (nan0 && nan1) ||                              // no hands
                (nan0 && (h1 == 1.0f)) ||                      // only hand1, right
                (nan1 && (h0 == 0.0f)) ||                      // only hand0, left
                (no_nan && eq && (h0 == 0.0f) && (p0 > p1)) || // both left
                (no_nan && eq && (h0 == 1.0f) && (p0 < p1));   // both right
            s_skip[t] = (unsigned char)skip;
        }
    }
    __syncthreads();

    // ---- Phase 2: write 65 float2 per thread, coalesced ----
    const long long rem = n_frames - frame0;
    const int frames_here = rem < (long long)FPB ? (int)rem : FPB;
    const long long chunk_f = frame0 * (long long)FRAME_LEN;  // float offset
    const float* __restrict__ Xc = X + chunk_f;
    float* __restrict__ Oc = out + chunk_f;

    // m = t + k*BLOCK is the float2 index in the chunk; frame = m/65, jj = m%65
    int fl = t / HALF;
    int jj = t - fl * HALF;
    for (int k = 0; k < HALF; ++k) {
        const int m = t + k * BLOCK;
        if (fl < frames_here) {
            float2 v;
            if (s_skip[fl]) {
                v = *(const float2*)(Xc + 2 * m);       // aligned copy path
            } else {
                const float* fb = Xc + fl * FRAME_LEN;  // rotate-by-65 path
                int j0 = 2 * jj + HALF;                 // 65..193
                if (j0 >= FRAME_LEN) j0 -= FRAME_LEN;
                int j1 = j0 + 1;
                if (j1 >= FRAME_LEN) j1 -= FRAME_LEN;   // only j0==129 wraps j1
                v.x = fb[j0];
                v.y = fb[j1];
            }
            *(float2*)(Oc + 2 * m) = v;
        }
        // advance (m += 256) => frame += 3, jj += 61 (256 = 3*65 + 61)
        jj += BLOCK - 3 * HALF;
        fl += 3;
        if (jj >= HALF) { jj -= HALF; fl += 1; }
    }
}

extern "C" void kernel_launch(void* const* d_in, const int* in_sizes, int n_in,
                              void* d_out, int out_size, void* d_ws, size_t ws_size,
                              hipStream_t stream) {
    const float* X = (const float*)d_in[0];
    float* out = (float*)d_out;
    const int n_frames = in_sizes[0] / FRAME_LEN;   // 256*1024 = 262144
    const int n_blocks = (n_frames + FPB - 1) / FPB;
    hand_sorter_kernel<<<n_blocks, BLOCK, 0, stream>>>(X, out, n_frames);
}

// Round 2
// 239.800 us; speedup vs baseline: 1.1281x; 1.1281x over previous
//
#include <hip/hip_runtime.h>

constexpr int FRAME_LEN = 130;   // floats per frame
constexpr int HALF      = 65;    // floats per hand block
constexpr int BLOCK     = 256;   // threads per block
constexpr int FPB       = 32;    // frames per block: LDS chunk = 32*130*4 = 16640 B
constexpr int CHUNK_F   = FPB * FRAME_LEN;   // 4160 floats
constexpr int CHUNK_V4  = CHUNK_F / 4;       // 1040 float4

// frame = idx / 130 for idx < 7825 via magic multiply (8067 = ceil(2^20/130))
__device__ __forceinline__ int div130(int idx) {
    return (int)(((unsigned)idx * 8067u) >> 20);
}

__global__ __launch_bounds__(BLOCK, 8)   // 8 waves/SIMD -> 8 blocks/CU, 100% occ
void hand_sorter_kernel(const float* __restrict__ X, float* __restrict__ out,
                        int n_frames) {
    __shared__ float s_buf[CHUNK_F];
    __shared__ unsigned char s_skip[FPB];

    const int t = threadIdx.x;
    const long long frame0 = (long long)blockIdx.x * FPB;
    const long long rem = (long long)n_frames - frame0;
    const int frames_here = rem < (long long)FPB ? (int)rem : FPB;
    const int nf = frames_here * FRAME_LEN;       // floats in this chunk
    const int n4 = (nf + 3) >> 2;                 // float4 slots (1040 full chunk)
    const long long base = frame0 * (long long)FRAME_LEN;
    const float4* __restrict__ Xv = (const float4*)(X + base);
    float4* __restrict__ Ov = (float4*)(out + base);

    // ---- Phase 1: stage chunk into LDS, identity float4 (coalesced) ----
    for (int i = t; i < n4; i += BLOCK) {
        *(float4*)(s_buf + 4 * i) = Xv[i];
    }
    __syncthreads();

    // ---- Phase 2: per-frame skip predicate from LDS ----
    if (t < frames_here) {
        const float* fr = s_buf + t * FRAME_LEN;
        const float h0 = fr[0];
        const float p0 = fr[1];
        const float h1 = fr[HALF];
        const float p1 = fr[HALF + 1];
        const bool nan0 = (h0 != h0);
        const bool nan1 = (h1 != h1);
        const bool no_nan = !nan0 && !nan1;
        const bool eq = (h0 == h1);
        const bool skip =
            (h1 > h0) ||
            (nan0 && nan1) ||
            (nan0 && (h1 == 1.0f)) ||
            (nan1 && (h0 == 0.0f)) ||
            (no_nan && eq && (h0 == 0.0f) && (p0 > p1)) ||
            (no_nan && eq && (h0 == 1.0f) && (p0 < p1));
        s_skip[t] = (unsigned char)skip;
    }
    __syncthreads();

    // ---- Phase 3: branch-free LDS gather, identity float4 stores ----
    for (int i = t; i < n4; i += BLOCK) {
        const int idx = 4 * i;
        float4 v;
        float* vp = (float*)&v;
        if (idx + 3 < nf) {
#pragma unroll
            for (int e = 0; e < 4; ++e) {
                const int ide = idx + e;
                const int fl = div130(ide);
                const int jj = ide - fl * FRAME_LEN;
                int sj = jj + (s_skip[fl] ? 0 : HALF);
                if (sj >= FRAME_LEN) sj -= FRAME_LEN;
                vp[e] = s_buf[fl * FRAME_LEN + sj];
            }
            Ov[i] = v;
        } else {
            // partial tail (never taken when n_frames % FPB == 0)
            for (int e = 0; e < 4; ++e) {
                const int ide = idx + e;
                if (ide < nf) {
                    const int fl = div130(ide);
                    const int jj = ide - fl * FRAME_LEN;
                    int sj = jj + (s_skip[fl] ? 0 : HALF);
                    if (sj >= FRAME_LEN) sj -= FRAME_LEN;
                    out[base + ide] = s_buf[fl * FRAME_LEN + sj];
                }
            }
        }
    }
}

extern "C" void kernel_launch(void* const* d_in, const int* in_sizes, int n_in,
                              void* d_out, int out_size, void* d_ws, size_t ws_size,
                              hipStream_t stream) {
    const float* X = (const float*)d_in[0];
    float* out = (float*)d_out;
    const int n_frames = in_sizes[0] / FRAME_LEN;   // 262144
    const int n_blocks = (n_frames + FPB - 1) / FPB;
    hand_sorter_kernel<<<n_blocks, BLOCK, 0, stream>>>(X, out, n_frames);
}